// Round 9
// baseline (1202.355 us; speedup 1.0000x reference)
//
#include <hip/hip_runtime.h>

typedef _Float16 f16;
typedef _Float16 f16x2 __attribute__((ext_vector_type(2)));
typedef _Float16 f16x8 __attribute__((ext_vector_type(8)));
typedef float    f32x4 __attribute__((ext_vector_type(4)));
typedef int      i32x4 __attribute__((ext_vector_type(4)));
typedef unsigned int u32;
typedef unsigned short u16;

#define DEVI static __device__ __forceinline__

static constexpr int LDT = 40;    // lds row stride (halves) for 64x32 tiles (+8 pad)
static constexpr int LDA = 264;   // lds row stride for 64x256 resident A tiles

DEVI float tanh_c(float x){
  x = fminf(fmaxf(x, -15.f), 15.f);
  float e = __expf(2.f*x);
  return (e - 1.f)/(e + 1.f);
}
DEVI float sig_f(float x){ return __builtin_amdgcn_rcpf(1.f + __expf(-x)); }
DEVI float tanh_f(float x){ return 1.f - 2.f*__builtin_amdgcn_rcpf(1.f + __expf(2.f*x)); }
DEVI float wmax16(float v){
  #pragma unroll
  for (int m=1;m<16;m<<=1) v = fmaxf(v, __shfl_xor(v, m, 64));
  return v;
}
DEVI float wsum16(float v){
  #pragma unroll
  for (int m=1;m<16;m<<=1) v += __shfl_xor(v, m, 64);
  return v;
}
DEVI f16x8 frag_ld(const f16* p){ return *(const f16x8*)p; }
DEVI void stage_tileh(int t256, const f16* src, int ld, f16* dst){
  int row = t256>>2, qq = t256&3;
  *(f16x8*)(dst + row*LDT + qq*8) = *(const f16x8*)(src + (size_t)row*ld + qq*8);
}
#define ZERO4(acc) { f32x4 _z = {0.f,0.f,0.f,0.f}; acc[0]=_z; acc[1]=_z; acc[2]=_z; acc[3]=_z; }

// 64x64 NT MFMA tile (t256 = thread id within the 256-thread tile team)
DEVI void gemm64h(int t256, const f16* A, int lda, const f16* Bm, int ldb, int K,
                  f16* lA, f16* lB, f32x4 acc[4]){
  const int lane = t256 & 63, wv = t256 >> 6;
  const int l15 = lane & 15, kq = lane >> 4;
  for (int k0=0; k0<K; k0+=32){
    __syncthreads();
    stage_tileh(t256, A + k0, lda, lA);
    stage_tileh(t256, Bm + k0, ldb, lB);
    __syncthreads();
    f16x8 af = frag_ld(lA + (16*wv + l15)*LDT + kq*8);
    #pragma unroll
    for (int nt=0; nt<4; nt++){
      f16x8 bf = frag_ld(lB + (16*nt + l15)*LDT + kq*8);
      acc[nt] = __builtin_amdgcn_mfma_f32_16x16x32_f16(af, bf, acc[nt], 0,0,0);
    }
  }
}

// ---------------- fused prep 1: f16 casts, transposes, Whh absmax ----------------
__global__ __launch_bounds__(256) void k_prep1(
    const float* __restrict__ eWih, const float* __restrict__ dWih, const float* __restrict__ Tm,
    const float* __restrict__ gconv, const float* __restrict__ gdec,
    const float* __restrict__ eWhh, const float* __restrict__ dWhh,
    f16* __restrict__ Wihe, f16* __restrict__ Wihd, f16* __restrict__ Tf,
    f16* __restrict__ gcT, f16* __restrict__ gdT, u32* __restrict__ wsc)
{
  const int bid = blockIdx.x, tid = threadIdx.x;
  if (bid < 512){ int i = bid*256 + tid; Wihe[i] = (f16)eWih[i]; }
  else if (bid < 1024){ int i = (bid-512)*256 + tid; Wihd[i] = (f16)dWih[i]; }
  else if (bid < 1536){ int i = (bid-1024)*256 + tid; Tf[i] = (f16)Tm[i]; }
  else if (bid < 2816){
    int id = bid - 1536;              // k*256+fi : 1280
    gcT[(size_t)tid*1280 + id] = (f16)gconv[(size_t)id*256 + tid];
  } else if (bid < 4864){
    int v = bid - 2816;               // 0..2047
    f16 val = (f16)0.f;
    if (v < 2000) val = (f16)gdec[(size_t)tid*2000 + v];
    gdT[(size_t)v*256 + tid] = val;
  } else {
    const float* W = (bid < 5120) ? eWhh : dWhh;
    u32* ws = wsc + ((bid < 5120) ? 0 : 1);
    int sb = (bid < 5120) ? (bid - 4864) : (bid - 5120);
    int i = (sb*256 + tid)*4;
    float m = 0.f;
    #pragma unroll
    for (int j=0;j<4;j++) m = fmaxf(m, fabsf(W[i+j]));
    #pragma unroll
    for (int d=1; d<64; d<<=1) m = fmaxf(m, __shfl_xor(m, d, 64));
    if ((tid & 63) == 0) atomicMax(ws, __float_as_uint(m));
  }
}

// quantize Whh into gate-packed i8 MFMA A-fragments (body).
// frag = (w*8 + t8)*4 + kt; lane l: r15=l&15 -> u4=r15>>2, g=r15&3;
// unit = w*32 + t8*4 + u4; row = g*256 + unit; k = kt*64 + (l>>4)*16 + (0..15)
DEVI void wq8_body(const float* Whh, const u32* ws, i32x4* Wq, int frag, int l){
  const int kt = frag & 3, t8 = (frag >> 2) & 7, w = frag >> 5;
  const int r15 = l & 15;
  const int u4 = r15 >> 2, g = r15 & 3;
  const int unit = w*32 + t8*4 + u4;
  const int row = g*256 + unit;
  const int k0  = kt*64 + (l >> 4)*16;
  const float scale = 127.f / __uint_as_float(ws[0]);
  int dw[4];
  #pragma unroll
  for (int d=0; d<4; d++){
    u32 acc = 0;
    #pragma unroll
    for (int j=0; j<4; j++){
      float q = __builtin_rintf(Whh[(size_t)row*256 + k0 + d*4 + j] * scale);
      int qi = (int)fminf(fmaxf(q, -127.f), 127.f);
      acc |= ((u32)qi & 0xffu) << (8*j);
    }
    dw[d] = (int)acc;
  }
  i32x4 v = { dw[0], dw[1], dw[2], dw[3] };
  Wq[(size_t)frag*64 + l] = v;
}

// ---------------- fused prep 2: wq8 (e,d), epad, embeddings ----------------
__global__ __launch_bounds__(256) void k_prep2(
    const float* __restrict__ eWhh, const float* __restrict__ dWhh, const u32* __restrict__ wsc,
    i32x4* __restrict__ Wq8e, i32x4* __restrict__ Wq8d,
    const int* __restrict__ xs, const int* __restrict__ ys,
    const float* __restrict__ gemb, const float* __restrict__ eemb, const float* __restrict__ demb,
    f16* __restrict__ epad, f16* __restrict__ xemb, f16* __restrict__ yemb)
{
  const int bid = blockIdx.x, tid = threadIdx.x;
  if (bid < 64){
    wq8_body(eWhh, wsc + 0, Wq8e, bid*4 + (tid >> 6), tid & 63);
  } else if (bid < 128){
    wq8_body(dWhh, wsc + 1, Wq8d, (bid-64)*4 + (tid >> 6), tid & 63);
  } else if (bid < 128 + 16512){
    int id = bid - 128;               // b*516+p
    int b = id / 516, p = id % 516;
    float v = 0.f;
    if (p >= 2 && p < 514){ int idx = xs[b*512 + p - 2]; v = tanh_c(gemb[(size_t)idx*256 + tid]); }
    epad[(size_t)id*256 + tid] = (f16)v;
  } else {
    int vb = bid - (128 + 16512);     // 0..16383
    int id = vb*2 + (tid >> 7);       // 0..32767
    int f = tid & 127;
    bool dec = id >= 32*512; int id2 = dec ? id - 32*512 : id;
    int idx = dec ? ys[id2] : xs[id2];
    if (idx < 4) idx = 0;
    const float* src = (dec ? demb : eemb) + (size_t)idx*128;
    (dec ? yemb : xemb)[(size_t)id2*128 + f] = (f16)src[f];
  }
}

// ---------------- GEMM bodies ----------------
DEVI void conv_body(int t256, int m0, int n0, const f16* epad, const f16* gcT, f16* tf,
                    f16* lA, f16* lB){
  const int b = m0 >> 9, n = m0 & 511;
  f32x4 acc[4]; ZERO4(acc);
  gemm64h(t256, epad + ((size_t)b*516 + n)*256, 256, gcT + (size_t)n0*1280, 1280, 1280, lA, lB, acc);
  const int lane=t256&63, wv=t256>>6, l15=lane&15, kq=lane>>4;
  #pragma unroll
  for (int nt=0;nt<4;nt++)
    #pragma unroll
    for (int r=0;r<4;r++)
      tf[(size_t)(m0 + 16*wv + 4*kq + r)*256 + n0 + nt*16 + l15] = (f16)tanh_c(acc[nt][r]);
}

// U output permuted to unit-major: col' = unit*4 + gate
DEVI void ku_body(int t256, int m0, int n0, const f16* X, const f16* Wih,
                  const float* bias, f16* U, f16* lA, f16* lB){
  f32x4 acc[4]; ZERO4(acc);
  gemm64h(t256, X + (size_t)m0*128, 128, Wih + (size_t)n0*128, 128, 128, lA, lB, acc);
  const int lane=t256&63, wv=t256>>6, l15=lane&15, kq=lane>>4;
  #pragma unroll
  for (int nt=0;nt<4;nt++){
    int n = n0 + nt*16 + l15;
    float bv = bias[n];
    int cnew = (n & 255)*4 + (n >> 8);
    #pragma unroll
    for (int r=0;r<4;r++)
      U[(size_t)(m0 + 16*wv + 4*kq + r)*1024 + cnew] = (f16)(acc[nt][r] + bv);
  }
}

// ---------------- fused prep 3: conv + enc input-gate GEMM ----------------
__global__ __launch_bounds__(256,4) void k_prep3(
    const f16* __restrict__ epad, const f16* __restrict__ gcT, f16* __restrict__ tf,
    const f16* __restrict__ xemb, const f16* __restrict__ Wihe,
    const float* __restrict__ eb, f16* __restrict__ Uenc)
{
  __shared__ f16 lA[64*LDT], lB[64*LDT];
  const int bid = blockIdx.x;
  if (bid < 1024){
    conv_body(threadIdx.x, (bid >> 2)*64, (bid & 3)*64, epad, gcT, tf, lA, lB);
  } else {
    int vb = bid - 1024;              // 0..4095
    ku_body(threadIdx.x, (vb >> 4)*64, (vb & 15)*64, xemb, Wihe, eb, Uenc, lA, lB);
  }
}

DEVI void th_body(int t256, int m0, int n0, const f16* henh, const f16* Tf, f16* Th,
                  f16* lA, f16* lB){
  f32x4 acc[4]; ZERO4(acc);
  gemm64h(t256, henh + (size_t)m0*512, 512, Tf + (size_t)n0*512, 512, 512, lA, lB, acc);
  const int lane=t256&63, wv=t256>>6, l15=lane&15, kq=lane>>4;
  #pragma unroll
  for (int nt=0;nt<4;nt++)
    #pragma unroll
    for (int r=0;r<4;r++)
      Th[(size_t)(m0 + 16*wv + 4*kq + r)*256 + n0 + nt*16 + l15] = (f16)acc[nt][r];
}

// pass1 (512-thr): halves split the 8 n-chunks; shared lA; per-half lB/mx/se; merged at end
DEVI void pass1_body(int tid, int mt, int ns, const f16* tf, const f16* gdT,
                     float* mxp, float* sep, f16* lA, f16* lB2, float* mxs2, float* ses2){
  const int half = tid >> 8, t256 = tid & 255;
  const int lane = tid & 63, wv = t256 >> 6, l15 = lane & 15, kq = lane >> 4;
  f16* lB = lB2 + half*(64*LDT);
  {
    const f16* A = tf + (size_t)mt*64*256;
    int row = tid >> 3, c8 = tid & 7;
    #pragma unroll
    for (int q=0;q<4;q++)
      *(f16x8*)(lA + row*LDA + c8*32 + q*8) = *(const f16x8*)(A + (size_t)row*256 + c8*32 + q*8);
  }
  if (t256 < 64){ mxs2[half*64 + t256] = -1e30f; ses2[half*64 + t256] = 0.f; }
  __syncthreads();
  for (int nci=0; nci<4; nci++){
    const int nc = half*4 + nci;
    const int nbase = ns*512 + nc*64;
    const f16* Bm = gdT + (size_t)nbase*256;
    f32x4 acc[4]; ZERO4(acc);
    for (int k0=0; k0<256; k0+=32){
      __syncthreads();
      stage_tileh(t256, Bm + k0, 256, lB);
      __syncthreads();
      f16x8 af = frag_ld(lA + (16*wv + l15)*LDA + k0 + kq*8);
      #pragma unroll
      for (int nt=0; nt<4; nt++){
        f16x8 bf = frag_ld(lB + (16*nt + l15)*LDT + kq*8);
        acc[nt] = __builtin_amdgcn_mfma_f32_16x16x32_f16(af, bf, acc[nt], 0,0,0);
      }
    }
    #pragma unroll
    for (int r=0;r<4;r++){
      float av[4]; float cm = -1e30f;
      #pragma unroll
      for (int nt=0;nt<4;nt++){
        int gcol = nbase + nt*16 + l15;
        float a = (gcol < 2000) ? acc[nt][r] : -1e30f;
        av[nt] = a; cm = fmaxf(cm, a);
      }
      cm = wmax16(cm);
      int rr = half*64 + 16*wv + 4*kq + r;
      float old = mxs2[rr];
      float nm = fmaxf(old, cm);
      float ss = 0.f;
      #pragma unroll
      for (int nt=0;nt<4;nt++) ss += __expf(av[nt] - nm);
      ss = wsum16(ss);
      if (l15 == 0){
        ses2[rr] = ses2[rr]*__expf(old - nm) + ss;
        mxs2[rr] = nm;
      }
    }
  }
  __syncthreads();
  if (tid < 64){
    float m0 = mxs2[tid], m1 = mxs2[64+tid];
    float nm = fmaxf(m0, m1);
    float se = ses2[tid]*__expf(m0-nm) + ses2[64+tid]*__expf(m1-nm);
    mxp[(size_t)ns*16384 + mt*64 + tid] = nm;
    sep[(size_t)ns*16384 + mt*64 + tid] = se;
  }
}

__global__ void k_comb1(const float* __restrict__ mxp, const float* __restrict__ sep,
                        float* __restrict__ mx, float* __restrict__ se){
  int m = blockIdx.x*256 + threadIdx.x;
  float best = -1e30f;
  #pragma unroll
  for (int k=0;k<4;k++) best = fmaxf(best, mxp[(size_t)k*16384 + m]);
  float s = 0.f;
  #pragma unroll
  for (int k=0;k<4;k++) s += sep[(size_t)k*16384 + m] * __expf(mxp[(size_t)k*16384 + m] - best);
  mx[m] = best; se[m] = s;
}

DEVI void pass2_body(int t256, int it, int jt, int b, const f16* tf, const f16* gdT,
                     const int* ys, const float* mx, const float* se, f16* scT,
                     f16* lA, f16* lB, int* jv){
  const int lane=t256&63, wv=t256>>6, l15=lane&15, kq=lane>>4;
  if (t256<64) jv[t256] = ys[b*512 + jt*64 + t256];
  const f16* A = tf + ((size_t)b*512 + it*64)*256;
  f32x4 acc[4]; ZERO4(acc);
  for (int k0=0;k0<256;k0+=32){
    __syncthreads();
    stage_tileh(t256, A + k0, 256, lA);
    { int row=t256>>2, qq=t256&3;
      *(f16x8*)(lB + row*LDT + qq*8) = *(const f16x8*)(gdT + (size_t)jv[row]*256 + k0 + qq*8); }
    __syncthreads();
    f16x8 af = frag_ld(lA + (16*wv+l15)*LDT + kq*8);
    #pragma unroll
    for (int nt=0;nt<4;nt++){
      f16x8 bf = frag_ld(lB + (16*nt+l15)*LDT + kq*8);
      acc[nt] = __builtin_amdgcn_mfma_f32_16x16x32_f16(af, bf, acc[nt], 0,0,0);
    }
  }
  float mxv[4], rsev[4];
  #pragma unroll
  for (int r=0;r<4;r++){
    int i_ = it*64 + 16*wv + 4*kq + r;
    mxv[r] = mx[b*512 + i_];
    rsev[r] = 1.f / se[b*512 + i_];
  }
  #pragma unroll
  for (int nt=0;nt<4;nt++){
    int j_ = jt*64 + nt*16 + l15;
    #pragma unroll
    for (int r=0;r<4;r++){
      int i_ = it*64 + 16*wv + 4*kq + r;
      scT[((size_t)b*512 + j_)*512 + i_] = (f16)(__expf(acc[nt][r] - mxv[r]) * rsev[r]);
    }
  }
}

// fused eij -> softmax over i -> <scores,align> -> -sum log, direct atomicAdd
__global__ __launch_bounds__(256,2) void k_final2(const f16* __restrict__ hdec, const f16* __restrict__ Th,
                                                  const f16* __restrict__ scT, float* __restrict__ out){
  __shared__ f16 lA[64*LDA];
  __shared__ f16 lB[64*LDT];
  __shared__ float mx_s[64], den_s[64], num_s[64];
  const int jt = blockIdx.x, b = blockIdx.y;
  const int tid = threadIdx.x, lane=tid&63, wv=tid>>6, l15=lane&15, kq=lane>>4;
  {
    const f16* A = hdec + ((size_t)b*512 + jt*64)*256;
    int row = tid>>2, qq = tid&3;
    #pragma unroll
    for (int c=0;c<8;c++)
      *(f16x8*)(lA + row*LDA + c*32 + qq*8) = *(const f16x8*)(A + (size_t)row*256 + c*32 + qq*8);
  }
  if (tid<64){ mx_s[tid]=-1e30f; den_s[tid]=0.f; num_s[tid]=0.f; }
  __syncthreads();
  for (int ic=0; ic<8; ic++){
    const int i0 = ic*64;
    const f16* Bm = Th + ((size_t)b*512 + i0)*256;
    f32x4 acc[4]; ZERO4(acc);
    for (int k0=0;k0<256;k0+=32){
      __syncthreads();
      stage_tileh(tid, Bm + k0, 256, lB);
      __syncthreads();
      f16x8 af = frag_ld(lA + (16*wv+l15)*LDA + k0 + kq*8);
      #pragma unroll
      for (int nt=0;nt<4;nt++){
        f16x8 bf = frag_ld(lB + (16*nt+l15)*LDT + kq*8);
        acc[nt] = __builtin_amdgcn_mfma_f32_16x16x32_f16(af, bf, acc[nt], 0,0,0);
      }
    }
    #pragma unroll
    for (int r=0;r<4;r++){
      int jl = 16*wv + 4*kq + r;
      float av[4]; float cm=-1e30f;
      #pragma unroll
      for (int nt=0;nt<4;nt++){ av[nt]=acc[nt][r]; cm=fmaxf(cm,av[nt]); }
      cm = wmax16(cm);
      float old = mx_s[jl], nm = fmaxf(old, cm);
      float ds=0.f, nsum=0.f;
      const size_t srow = ((size_t)b*512 + jt*64 + jl)*512;
      #pragma unroll
      for (int nt=0;nt<4;nt++){
        float e = __expf(av[nt]-nm);
        float sc = (float)scT[srow + i0 + nt*16 + l15];
        ds += e; nsum += sc*e;
      }
      ds = wsum16(ds); nsum = wsum16(nsum);
      if (l15==0){
        float fac = __expf(old-nm);
        den_s[jl] = den_s[jl]*fac + ds;
        num_s[jl] = num_s[jl]*fac + nsum;
        mx_s[jl] = nm;
      }
    }
  }
  __syncthreads();
  if (tid < 64){
    float lp = __logf(num_s[tid]) - __logf(den_s[tid]);   // mx cancels
    #pragma unroll
    for (int m=1;m<64;m<<=1) lp += __shfl_xor(lp, m, 64);
    if (tid == 0) atomicAdd(out, -lp);
  }
}

// ---------------- LSTM v8: gate-packed i8 MFMA + deferred global stores ----------------
// (layout identical to v7; global h-stores issued AFTER the step barrier, one iteration late,
//  so the pre-barrier s_waitcnt vmcnt(0) no longer waits on them)
DEVI void lstm_core(char* smem, const f16* U, const i32x4* Wq, const u32* ws,
                    u16* hout, float* hTcT, u16* hdec0, int nsteps, int mode, int bid)
{
  f16* Ub  = (f16*)smem;             // 2 buffers x 4*1032 halves = 16512 B
  char* h8b = smem + 16512;          // 2 buffers x 1024 B
  const int tid = threadIdx.x;
  const int lane = tid & 63, w = tid >> 6;
  const int l15 = lane & 15, kq = lane >> 4;
  const int s = l15 & 3, p = l15 >> 2;
  const int uA = w*32 + 8*p + kq;
  const int uB = uA + 4;

  int dir = 0, b0;
  if (mode == 0){ dir = bid >> 3; b0 = (bid & 7)*4; }
  else b0 = bid*4;

  const float zscale = __uint_as_float(ws[0]) * (1.f/(127.f*127.f));

  i32x4 aw[32];
  #pragma unroll
  for (int f=0; f<32; f++) aw[f] = Wq[(size_t)(w*32 + f)*64 + lane];

  float cA = 0.f, cB = 0.f;
  if (mode == 0){
    ((u32*)h8b)[tid] = 0u;           // 512 words = both buffers
  } else {
    const float* hp = hTcT + (size_t)(b0+s)*512;
    float hA = hp[uA], hB = hp[uB];
    cA = hp[256 + uA]; cB = hp[256 + uB];
    h8b[((uA>>4)*4 + s)*16 + (uA&15)] = (char)(int)__builtin_rintf(hA*127.f);
    h8b[((uB>>4)*4 + s)*16 + (uB&15)] = (char)(int)__builtin_rintf(hB*127.f);
  }

  const int s_st = tid >> 7, col = (tid & 127)*8;
  {
    int tp0 = dir ? (nsteps-1) : 0;
    *(int4*)&Ub[s_st*1032 + col] = *(const int4*)(U + ((size_t)(b0+s_st)*512 + tp0)*1024 + col);
  }
  __syncthreads();

  int cur = 0;
  u32 pk_pend = 0;
  u16* pr_pend = hout;               // overwritten before first use
  float hA_l = 0.f, hB_l = 0.f;
  #pragma unroll 1
  for (int t=0; t<nsteps; ++t){
    // deferred store of previous step's h (now after the barrier; retires during this step)
    if (t > 0){
      pr_pend[0] = (u16)(pk_pend & 0xffffu);
      pr_pend[4] = (u16)(pk_pend >> 16);
    }
    const int tpos = dir ? (nsteps-1-t) : t;
    int tn = dir ? (nsteps-2-t >= 0 ? nsteps-2-t : 0) : (t+1 < nsteps ? t+1 : nsteps-1);
    int4 pu = *(const int4*)(U + ((size_t)(b0+s_st)*512 + tn)*1024 + col);

    const char* hc = h8b + cur*1024;
    i32x4 bf[4];
    #pragma unroll
    for (int kt=0; kt<4; kt++)
      bf[kt] = *(const i32x4*)(hc + ((kt*4 + kq)*4 + s)*16);

    i32x4 acc[8];
    #pragma unroll
    for (int t8=0; t8<8; t8++){
      i32x4 d = {0,0,0,0};
      #pragma unroll
      for (int kt=0; kt<4; kt++)
        d = __builtin_amdgcn_mfma_i32_16x16x64_i8(aw[t8*4+kt], bf[kt], d, 0,0,0);
      acc[t8] = d;
    }

    // pick tiles 2p (uA) and 2p+1 (uB)
    i32x4 vA, vB;
    #pragma unroll
    for (int e=0; e<4; e++){
      int x0 = (p&1) ? acc[2][e] : acc[0][e];
      int x1 = (p&1) ? acc[6][e] : acc[4][e];
      vA[e] = (p&2) ? x1 : x0;
      int y0 = (p&1) ? acc[3][e] : acc[1][e];
      int y1 = (p&1) ? acc[7][e] : acc[5][e];
      vB[e] = (p&2) ? y1 : y0;
    }

    const f16* upA = Ub + cur*4128 + s*1032 + uA*4;
    const f16* upB = Ub + cur*4128 + s*1032 + uB*4;
    {
      float z0 = fmaf((float)vA[0], zscale, (float)upA[0]);
      float z1 = fmaf((float)vA[1], zscale, (float)upA[1]);
      float z2 = fmaf((float)vA[2], zscale, (float)upA[2]);
      float z3 = fmaf((float)vA[3], zscale, (float)upA[3]);
      cA = sig_f(z1)*cA + sig_f(z0)*tanh_f(z2);
      hA_l = sig_f(z3)*tanh_f(cA);
    }
    {
      float z0 = fmaf((float)vB[0], zscale, (float)upB[0]);
      float z1 = fmaf((float)vB[1], zscale, (float)upB[1]);
      float z2 = fmaf((float)vB[2], zscale, (float)upB[2]);
      float z3 = fmaf((float)vB[3], zscale, (float)upB[3]);
      cB = sig_f(z1)*cB + sig_f(z0)*tanh_f(z2);
      hB_l = sig_f(z3)*tanh_f(cB);
    }

    const int nxt = cur ^ 1;
    char* hn = h8b + nxt*1024;
    hn[((uA>>4)*4 + s)*16 + (uA&15)] = (char)(int)__builtin_rintf(hA_l*127.f);
    hn[((uB>>4)*4 + s)*16 + (uB&15)] = (char)(int)__builtin_rintf(hB_l*127.f);
    *(int4*)&Ub[nxt*4128 + s_st*1032 + col] = pu;

    // stash global store for next iteration
    f16 fA = (f16)hA_l, fB = (f16)hB_l;
    pk_pend = (u32)__builtin_bit_cast(u16, fA) | ((u32)__builtin_bit_cast(u16, fB) << 16);
    if (mode == 0)
      pr_pend = hout + ((size_t)(b0+s)*512 + tpos)*512 + dir*256 + uA;
    else
      pr_pend = hout + ((size_t)(b0+s)*512 + (t+1))*256 + uA;

    __syncthreads();
    cur = nxt;
  }
  // flush last pending store + final state
  pr_pend[0] = (u16)(pk_pend & 0xffffu);
  pr_pend[4] = (u16)(pk_pend >> 16);
  if (mode == 0 && !dir){
    hdec0[(size_t)(b0+s)*512*256 + uA] = (u16)(pk_pend & 0xffffu);
    hdec0[(size_t)(b0+s)*512*256 + uB] = (u16)(pk_pend >> 16);
    float* hp = hTcT + (size_t)(b0+s)*512;
    hp[uA] = hA_l; hp[uB] = hB_l;
    hp[256+uA] = cA; hp[256+uB] = cB;
  }
}

// ---------------- mega dispatches (no intra-dispatch dependencies) ----------------
__global__ __launch_bounds__(512,2) void k_mega_enc(
    const f16* __restrict__ Uenc, const i32x4* __restrict__ Wqe, const u32* __restrict__ wse,
    u16* __restrict__ henh, float* __restrict__ hTcT, u16* __restrict__ hdec0,
    const f16* __restrict__ tf, const f16* __restrict__ gdT,
    float* __restrict__ mxp, float* __restrict__ sep,
    const f16* __restrict__ yemb, const f16* __restrict__ Wihd,
    const float* __restrict__ db, f16* __restrict__ Udec)
{
  __shared__ __align__(16) char smem[45056];
  const int bid = blockIdx.x;
  const int tid = threadIdx.x;
  if (bid < 16){
    lstm_core(smem, Uenc, Wqe, wse, henh, hTcT, hdec0, 512, 0, bid);
  } else if (bid < 1040){
    int vb = bid - 16;                 // 0..1023
    int mt = vb >> 2;                  // 0..255
    int ns = vb & 3;                   // 0..3
    pass1_body(tid, mt, ns, tf, gdT, mxp, sep,
               (f16*)smem, (f16*)(smem + 33792), (float*)(smem + 44032), (float*)(smem + 44544));
  } else {
    int vb = bid - 1040;               // 0..2047
    int half = tid >> 8, t256 = tid & 255;
    int vbm = vb >> 4, ny = vb & 15;
    int m0 = (vbm*2 + half)*64;
    int n0 = ny*64;
    char* base = smem + half*10240;
    ku_body(t256, m0, n0, yemb, Wihd, db, Udec, (f16*)base, (f16*)(base + 5120));
  }
}

__global__ __launch_bounds__(512,2) void k_mega_dec(
    const f16* __restrict__ Udec, const i32x4* __restrict__ Wqd, const u32* __restrict__ wsd,
    u16* __restrict__ hdec, float* __restrict__ hTcT,
    const f16* __restrict__ tf, const f16* __restrict__ gdT, const int* __restrict__ ys,
    const float* __restrict__ mx, const float* __restrict__ se, f16* __restrict__ scT,
    const f16* __restrict__ henh, const f16* __restrict__ Tf, f16* __restrict__ Th)
{
  __shared__ __align__(16) char smem[24576];
  const int bid = blockIdx.x;
  const int tid = threadIdx.x;
  if (bid < 8){
    lstm_core(smem, Udec, Wqd, wsd, hdec, hTcT, hdec, 511, 1, bid);
  } else if (bid < 1032){
    int vb = bid - 8;                  // 0..1023
    int half = tid >> 8, t256 = tid & 255;
    int b = vb >> 5, rem = vb & 31;
    int jt = rem >> 2, it = (rem & 3)*2 + half;
    char* base = smem + half*10496;
    pass2_body(t256, it, jt, b, tf, gdT, ys, mx, se, scT,
               (f16*)base, (f16*)(base + 5120), (int*)(base + 10240));
  } else {
    int vb = bid - 1032;               // 0..511
    int half = tid >> 8, t256 = tid & 255;
    int m0 = ((vb >> 2)*2 + half)*64;
    int n0 = (vb & 3)*64;
    char* base = smem + half*10240;
    th_body(t256, m0, n0, henh, Tf, Th, (f16*)base, (f16*)(base + 5120));
  }
}

// ---------------- host ----------------
extern "C" void kernel_launch(void* const* d_in, const int* in_sizes, int n_in,
                              void* d_out, int out_size, void* d_ws, size_t ws_size,
                              hipStream_t stream)
{
  (void)in_sizes; (void)n_in; (void)out_size;
  const int*   xs    = (const int*)d_in[0];
  const int*   ys    = (const int*)d_in[1];
  const float* gemb  = (const float*)d_in[2];
  const float* gconv = (const float*)d_in[3];
  const float* gdec  = (const float*)d_in[4];
  const float* eemb  = (const float*)d_in[5];
  const float* demb  = (const float*)d_in[6];
  const float* eWih  = (const float*)d_in[7];
  const float* eWhh  = (const float*)d_in[8];
  const float* eb    = (const float*)d_in[9];
  const float* dWih  = (const float*)d_in[10];
  const float* dWhh  = (const float*)d_in[11];
  const float* db    = (const float*)d_in[12];
  const float* Tm    = (const float*)d_in[13];

  char* wsb = (char*)d_ws;
  size_t off = 0;
  auto take = [&](size_t bytes)->char*{ char* p = wsb + off; off += (bytes + 255) & ~(size_t)255; return p; };
  f16* epad  = (f16*)take((size_t)32*516*256*2);
  f16* tf    = (f16*)take((size_t)32*512*256*2);
  f16* xemb  = (f16*)take((size_t)32*512*128*2);
  f16* yemb  = (f16*)take((size_t)32*512*128*2);
  f16* Uenc  = (f16*)take((size_t)32*512*1024*2);
  f16* Udec  = (f16*)take((size_t)32*512*1024*2);
  f16* henh  = (f16*)take((size_t)32*512*512*2);
  f16* hdec  = (f16*)take((size_t)32*512*256*2);
  f16* Th    = (f16*)take((size_t)32*512*256*2);
  f16* scT   = (f16*)take((size_t)32*512*512*2);
  float* mx  = (float*)take((size_t)16384*4);
  float* se  = (float*)take((size_t)16384*4);
  float* mxp = (float*)take((size_t)4*16384*4);
  float* sep = (float*)take((size_t)4*16384*4);
  float* hTcT= (float*)take((size_t)32*512*4);
  f16* Wihe  = (f16*)take((size_t)1024*128*2);
  f16* Wihd  = (f16*)take((size_t)1024*128*2);
  f16* Tf    = (f16*)take((size_t)256*512*2);
  f16* gcT   = (f16*)take((size_t)256*1280*2);
  f16* gdT   = (f16*)take((size_t)2048*256*2);
  i32x4* Wq8e = (i32x4*)take((size_t)256*64*16);
  i32x4* Wq8d = (i32x4*)take((size_t)256*64*16);
  u32* wsc   = (u32*)take(8);
  if (off > ws_size) return;

  hipMemsetAsync(d_out, 0, sizeof(float), stream);
  hipMemsetAsync(wsc, 0, 8, stream);

  // prep (3 fused launches)
  k_prep1<<<dim3(5376), 256, 0, stream>>>(eWih, dWih, Tm, gconv, gdec, eWhh, dWhh,
                                          Wihe, Wihd, Tf, gcT, gdT, wsc);
  k_prep2<<<dim3(128 + 16512 + 16384), 256, 0, stream>>>(eWhh, dWhh, wsc, Wq8e, Wq8d,
                                                         xs, ys, gemb, eemb, demb,
                                                         epad, xemb, yemb);
  k_prep3<<<dim3(5120), 256, 0, stream>>>(epad, gcT, tf, xemb, Wihe, eb, Uenc);

  // mega-enc: [0,16) lstm_enc | [16,1040) pass1 | [1040,3088) k_u dec (dual 256-thr teams)
  k_mega_enc<<<dim3(3088), 512, 0, stream>>>(Uenc, Wq8e, wsc + 0, (u16*)henh, hTcT, (u16*)hdec,
                                             tf, gdT, mxp, sep, yemb, Wihd, db, Udec);
  k_comb1<<<dim3(64), 256, 0, stream>>>(mxp, sep, mx, se);

  // mega-dec: [0,8) lstm_dec | [8,1032) pass2 | [1032,1544) k_th
  k_mega_dec<<<dim3(1544), 512, 0, stream>>>(Udec, Wq8d, wsc + 1, (u16*)hdec, hTcT,
                                             tf, gdT, ys, mx, se, scT, henh, Tf, Th);

  // fused alignment-score epilogue (direct atomicAdd into d_out)
  k_final2<<<dim3(8,32), 256, 0, stream>>>(hdec, Th, scT, (float*)d_out);
}